// Round 13
// baseline (118.080 us; speedup 1.0000x reference)
//
#include <hip/hip_runtime.h>
#include <math.h>

#define S_    10
#define C_    48
#define HWD   64
#define M_    512
#define PADK  4
#define PAIRS 20           // S_ * N(=2)
#define XPITCH 9           // xs LDS pitch

// Compact gathered y layout: GY[(s*96 + 2*c + n)*512 + m]
// ws layout (float offsets)
#define OFF_GY  0
#define OFF_CM  491520                    // colmax (uint-encoded floats), 10240
#define OFF_MU  (OFF_CM + PAIRS * M_)     // 480 floats (channel SUMS; /1024 at use)
#define OFF_CNT (OFF_MU + 480)            // 20 uint pair-arrival counters
#define OFF_ALL (OFF_CNT + 20)            // 1 uint global pair-done counter
#define OFF_PL  (OFF_ALL + 1)             // 20 float pair losses
#define ZERO_N  (10240 + 480 + 20 + 1 + 20)   // OFF_CM..OFF_PL contiguous

__device__ __forceinline__ int gidx(int n, int c, int h, int w, int d) {
  return (((n * C_ + c) * HWD + h) * HWD + w) * HWD + d;
}

// ---- kernel 1: gather y -> compact GY; channel sums via 2 atomicAdds ------
// 960 blocks x 256 thr; block = ((s,c), n). 2-partial float sum: a+b==b+a.
__global__ void k_gy(const float* __restrict__ y, const int* __restrict__ hi,
                     const int* __restrict__ wi, const int* __restrict__ di,
                     float* __restrict__ ws) {
  int b = blockIdx.x, t = threadIdx.x;
  int lane = t & 63, wv = t >> 6;
  int slice = b >> 1, half = b & 1;                  // half = n
  int s = slice / C_, c = slice % C_;
  int h0 = hi[s] - PADK, w0 = wi[s] - PADK, d0 = di[s] - PADK;
  float* dst = ws + OFF_GY + (s * 96 + 2 * c + half) * 512;
  float sum = 0.f;
#pragma unroll
  for (int j = 0; j < 2; ++j) {
    int m = t + 256 * j;
    float v = y[gidx(half, c, h0 + (m >> 6), w0 + ((m >> 3) & 7), d0 + (m & 7))];
    dst[m] = v;                        // coalesced compact store
    sum += v;
  }
  __shared__ float red[4];
#pragma unroll
  for (int off = 32; off; off >>= 1) sum += __shfl_xor(sum, off);
  if (lane == 0) red[wv] = sum;
  __syncthreads();
  if (t == 0)
    atomicAdd(ws + OFF_MU + s * C_ + c, red[0] + red[1] + red[2] + red[3]);
}

// ---- kernel 2: center + L2-normalize y IN PLACE (L2-resident) -------------
// 160 blocks x 256 thr; 4 lanes per column (12 channels each).
__global__ void k_ny(float* __restrict__ ws) {
  int g = blockIdx.x * 256 + threadIdx.x;   // 0..40959
  int col = g >> 2;                         // 0..10239
  int q = threadIdx.x & 3;                  // channel quarter
  int pair = col >> 9, m = col & 511;
  int s = pair >> 1, n = pair & 1;
  float* base = ws + OFF_GY + (s * 96 + n) * 512 + m;
  const float* mus = ws + OFF_MU + s * C_;
  int c0 = q * 12;
  float v[12], ss = 0.f;
#pragma unroll
  for (int j = 0; j < 12; ++j) {
    v[j] = base[(c0 + j) * 1024] - mus[c0 + j] * (1.0f / 1024.0f);
    ss += v[j] * v[j];
  }
  ss += __shfl_xor(ss, 1);             // combine 4 quarters (aligned group)
  ss += __shfl_xor(ss, 2);
  float sc = 1.0f / fmaxf(sqrtf(ss), 1e-12f);
#pragma unroll
  for (int j = 0; j < 12; ++j) base[(c0 + j) * 1024] = v[j] * sc;
}

// ---- kernel 3: x inline-gather+norm; y via LDS chunks; softmax; final -----
// 1280 blocks x 256 thr; block = (pair, tile of 8 rows); wave owns 2 rows.
// 5 blocks/CU x 4 waves = 20 waves/CU (~62% occ) hides LDS+stage latency;
// y consumed as 2x ds_read_b128 per channel (p = 4*lane+k mapping).
__global__ __launch_bounds__(256, 5) void k_main(const float* __restrict__ x,
                                                 const int* __restrict__ hi,
                                                 const int* __restrict__ wi,
                                                 const int* __restrict__ di,
                                                 float* __restrict__ ws,
                                                 float* __restrict__ out) {
  int b = blockIdx.x;
  int pair = b >> 6, tile = b & 63;
  int s = pair >> 1, n = pair & 1;
  int t = threadIdx.x, lane = t & 63, wv = t >> 6;

  __shared__ float xs[C_ * XPITCH];    // x tile [c][r], pitch 9
  __shared__ float mus[C_];
  __shared__ float ybuf[12 * 512];     // y chunk [cr][p], p-contiguous
  __shared__ unsigned cm[M_];          // per-p block colmax (uint bits)
  __shared__ float red[4];
  __shared__ unsigned arr;
  __shared__ int lastflag;

  int h0 = hi[s] - PADK, w0 = wi[s] - PADK, d0 = di[s] - PADK;
  if (t < C_) mus[t] = ws[OFF_MU + s * C_ + t] * (1.0f / 1024.0f);
  cm[t] = 0u;
  cm[t + 256] = 0u;
  // stage raw x tile: c = i>>3, r = i&7; global row m = tile*8 + r
  for (int i = t; i < 384; i += 256) {
    int c = i >> 3, r = i & 7;
    xs[c * XPITCH + r] =
        x[gidx(n, c, h0 + (tile >> 3), w0 + (tile & 7), d0 + r)];
  }
  __syncthreads();

  // center + per-column normalize: group g = t>>5 owns column r=g (32 lanes).
  {
    int grp = t >> 5, l32 = t & 31;
    float v0 = xs[l32 * XPITCH + grp] - mus[l32];          // c = l32
    float v1 = 0.f;
    if (l32 < 16) v1 = xs[(32 + l32) * XPITCH + grp] - mus[32 + l32];
    float ss = v0 * v0 + v1 * v1;
    ss += __shfl_xor(ss, 16); ss += __shfl_xor(ss, 8);
    ss += __shfl_xor(ss, 4);  ss += __shfl_xor(ss, 2);  ss += __shfl_xor(ss, 1);
    float sc = 1.0f / fmaxf(sqrtf(ss), 1e-12f);
    xs[l32 * XPITCH + grp] = v0 * sc;
    if (l32 < 16) xs[(32 + l32) * XPITCH + grp] = v1 * sc;
  }

  float acc[2][8];
#pragma unroll
  for (int r = 0; r < 2; ++r)
#pragma unroll
    for (int k = 0; k < 8; ++k) acc[r][k] = 0.f;

  const float* ysrc = ws + OFF_GY + (s * 96 + n) * 512;
  for (int chunk = 0; chunk < 4; ++chunk) {
    __syncthreads();                   // prev chunk consumed / x-norm done
#pragma unroll
    for (int i = 0; i < 6; ++i) {      // stage 12 channels: 1536 float4s
      int li = t + 256 * i;
      int cr = li >> 7, p4 = (li & 127) << 2;
      *(float4*)(ybuf + cr * 512 + p4) =
          *(const float4*)(ysrc + (chunk * 12 + cr) * 1024 + p4);
    }
    __syncthreads();
#pragma unroll
    for (int cr = 0; cr < 12; ++cr) {
      float4 y0 = *(const float4*)(ybuf + cr * 512 + 4 * lane);        // b128
      float4 y1 = *(const float4*)(ybuf + cr * 512 + 256 + 4 * lane);  // b128
      int c = chunk * 12 + cr;
      float xv0 = xs[c * XPITCH + wv * 2 + 0];   // wave-uniform broadcast
      float xv1 = xs[c * XPITCH + wv * 2 + 1];
      acc[0][0] += xv0 * y0.x; acc[0][1] += xv0 * y0.y;
      acc[0][2] += xv0 * y0.z; acc[0][3] += xv0 * y0.w;
      acc[0][4] += xv0 * y1.x; acc[0][5] += xv0 * y1.y;
      acc[0][6] += xv0 * y1.z; acc[0][7] += xv0 * y1.w;
      acc[1][0] += xv1 * y0.x; acc[1][1] += xv1 * y0.y;
      acc[1][2] += xv1 * y0.z; acc[1][3] += xv1 * y0.w;
      acc[1][4] += xv1 * y1.x; acc[1][5] += xv1 * y1.y;
      acc[1][6] += xv1 * y1.z; acc[1][7] += xv1 * y1.w;
    }
  }

  // epilogue: per-row min -> softmax -> per-p max over this wave's 2 rows
  float cm2[8];
#pragma unroll
  for (int k = 0; k < 8; ++k) cm2[k] = 0.f;
#pragma unroll
  for (int r = 0; r < 2; ++r) {
    float dmin = 3.4e38f;
#pragma unroll
    for (int k = 0; k < 8; ++k) {
      float d = 1.0f - acc[r][k];
      acc[r][k] = d;
      dmin = fminf(dmin, d);
    }
#pragma unroll
    for (int off = 32; off; off >>= 1) dmin = fminf(dmin, __shfl_xor(dmin, off));
    float inv = 2.0f / (dmin + 1e-5f); // logits <= 2, no overflow
    float e[8], sm = 0.f;
#pragma unroll
    for (int k = 0; k < 8; ++k) {
      e[k] = __expf(2.0f - acc[r][k] * inv);
      sm += e[k];
    }
#pragma unroll
    for (int off = 32; off; off >>= 1) sm += __shfl_xor(sm, off);
    float rs = 1.0f / sm;
#pragma unroll
    for (int k = 0; k < 8; ++k) cm2[k] = fmaxf(cm2[k], e[k] * rs);
  }
  // block-local colmax in LDS (p: k<4 -> 4*lane+k ; k>=4 -> 256+4*lane+k-4)
#pragma unroll
  for (int k = 0; k < 4; ++k)
    atomicMax(&cm[4 * lane + k], __float_as_uint(cm2[k]));
#pragma unroll
  for (int k = 4; k < 8; ++k)
    atomicMax(&cm[256 + 4 * lane + (k - 4)], __float_as_uint(cm2[k]));
  __syncthreads();
  unsigned* cmu = (unsigned*)(ws + OFF_CM) + pair * M_;
  if (cm[t]) atomicMax(&cmu[t], cm[t]);
  if (cm[t + 256]) atomicMax(&cmu[t + 256], cm[t + 256]);

  // ---- fused final: last block per pair reduces; last pair writes out ----
  __threadfence();
  if (t == 0) arr = atomicAdd((unsigned*)(ws + OFF_CNT) + pair, 1u);
  __syncthreads();
  if (arr == 63) {
    float sum = __uint_as_float(atomicOr(&cmu[t], 0u)) +
                __uint_as_float(atomicOr(&cmu[t + 256], 0u));
#pragma unroll
    for (int off = 32; off; off >>= 1) sum += __shfl_xor(sum, off);
    if (lane == 0) red[wv] = sum;
    if (t == 0) lastflag = 0;
    __syncthreads();
    if (t == 0) {
      float tot = red[0] + red[1] + red[2] + red[3];
      float loss = -logf(tot * (1.0f / 512.0f) + 1e-5f);
      atomicExch((unsigned*)(ws + OFF_PL) + pair, __float_as_uint(loss));
      __threadfence();
      unsigned d = atomicAdd((unsigned*)(ws + OFF_ALL), 1u);
      if (d == PAIRS - 1) lastflag = 1;
    }
    __syncthreads();
    if (lastflag && t < 32) {          // parallel 20-loss readback
      float v = (t < PAIRS)
                    ? __uint_as_float(atomicOr((unsigned*)(ws + OFF_PL) + t, 0u))
                    : 0.f;
#pragma unroll
      for (int off = 16; off; off >>= 1) v += __shfl_xor(v, off);
      if (t == 0) out[0] = v * (1.0f / (float)PAIRS);
    }
  }
}

extern "C" void kernel_launch(void* const* d_in, const int* in_sizes, int n_in,
                              void* d_out, int out_size, void* d_ws, size_t ws_size,
                              hipStream_t stream) {
  const float* x = (const float*)d_in[0];
  const float* y = (const float*)d_in[1];
  const int* hi = (const int*)d_in[2];
  const int* wi = (const int*)d_in[3];
  const int* di = (const int*)d_in[4];
  float* ws = (float*)d_ws;
  float* out = (float*)d_out;

  hipMemsetAsync(ws + OFF_CM, 0, ZERO_N * sizeof(float), stream);
  k_gy<<<960, 256, 0, stream>>>(y, hi, wi, di, ws);
  k_ny<<<160, 256, 0, stream>>>(ws);
  k_main<<<PAIRS * 64, 256, 0, stream>>>(x, hi, wi, di, ws, out);
}

// Round 14
// 72.176 us; speedup vs baseline: 1.6360x; 1.6360x over previous
//
#include <hip/hip_runtime.h>
#include <math.h>

#define S_    10
#define C_    48
#define HWD   64
#define M_    512
#define PADK  4
#define PAIRS 20           // S_ * N(=2)
#define YPITCH 516         // ybuf LDS pitch (516%32=4 -> 2-way alias = free)

// Compact gathered y layout: GY[(s*96 + 2*c + n)*512 + m]
// ws layout (float offsets)
#define OFF_GY  0
#define OFF_CM  491520                    // colmax (uint-encoded floats), 10240
#define OFF_MU  (OFF_CM + PAIRS * M_)     // 480 floats (channel SUMS; /1024 at use)
#define OFF_CNT (OFF_MU + 480)            // 20 uint pair-arrival counters
#define OFF_ALL (OFF_CNT + 20)            // 1 uint global pair-done counter
#define OFF_PL  (OFF_ALL + 1)             // 20 float pair losses
#define ZERO_N  (10240 + 480 + 20 + 1 + 20)   // OFF_CM..OFF_PL contiguous

__device__ __forceinline__ int gidx(int n, int c, int h, int w, int d) {
  return (((n * C_ + c) * HWD + h) * HWD + w) * HWD + d;
}

// ---- kernel 1: gather y -> compact GY; channel sums via 2 atomicAdds ------
// 960 blocks x 256 thr; block = ((s,c), n). 2-partial float sum: a+b==b+a.
__global__ void k_gy(const float* __restrict__ y, const int* __restrict__ hi,
                     const int* __restrict__ wi, const int* __restrict__ di,
                     float* __restrict__ ws) {
  int b = blockIdx.x, t = threadIdx.x;
  int lane = t & 63, wv = t >> 6;
  int slice = b >> 1, half = b & 1;                  // half = n
  int s = slice / C_, c = slice % C_;
  int h0 = hi[s] - PADK, w0 = wi[s] - PADK, d0 = di[s] - PADK;
  float* dst = ws + OFF_GY + (s * 96 + 2 * c + half) * 512;
  float sum = 0.f;
#pragma unroll
  for (int j = 0; j < 2; ++j) {
    int m = t + 256 * j;
    float v = y[gidx(half, c, h0 + (m >> 6), w0 + ((m >> 3) & 7), d0 + (m & 7))];
    dst[m] = v;                        // coalesced compact store
    sum += v;
  }
  __shared__ float red[4];
#pragma unroll
  for (int off = 32; off; off >>= 1) sum += __shfl_xor(sum, off);
  if (lane == 0) red[wv] = sum;
  __syncthreads();
  if (t == 0)
    atomicAdd(ws + OFF_MU + s * C_ + c, red[0] + red[1] + red[2] + red[3]);
}

// ---- kernel 2: center + L2-normalize y IN PLACE (L2-resident) -------------
// 160 blocks x 256 thr; 4 lanes per column (12 channels each).
__global__ void k_ny(float* __restrict__ ws) {
  int g = blockIdx.x * 256 + threadIdx.x;   // 0..40959
  int col = g >> 2;                         // 0..10239
  int q = threadIdx.x & 3;                  // channel quarter
  int pair = col >> 9, m = col & 511;
  int s = pair >> 1, n = pair & 1;
  float* base = ws + OFF_GY + (s * 96 + n) * 512 + m;
  const float* mus = ws + OFF_MU + s * C_;
  int c0 = q * 12;
  float v[12], ss = 0.f;
#pragma unroll
  for (int j = 0; j < 12; ++j) {
    v[j] = base[(c0 + j) * 1024] - mus[c0 + j] * (1.0f / 1024.0f);
    ss += v[j] * v[j];
  }
  ss += __shfl_xor(ss, 1);             // combine 4 quarters (aligned group)
  ss += __shfl_xor(ss, 2);
  float sc = 1.0f / fmaxf(sqrtf(ss), 1e-12f);
#pragma unroll
  for (int j = 0; j < 12; ++j) base[(c0 + j) * 1024] = v[j] * sc;
}

// ---- kernel 3: x inline-gather+norm; dist+softmax+colmax; fused final -----
// 320 blocks x 512 thr (8 waves); block = (pair, tile of 32 rows); wave owns
// 4 rows (acc[4][8]=32 VGPR). 2 waves/SIMD everywhere -> LDS/stage latency
// overlaps across waves (R9 had 1 wave/SIMD on 192 of 256 CUs).
__global__ __launch_bounds__(512, 2) void k_main(const float* __restrict__ x,
                                                 const int* __restrict__ hi,
                                                 const int* __restrict__ wi,
                                                 const int* __restrict__ di,
                                                 float* __restrict__ ws,
                                                 float* __restrict__ out) {
  int b = blockIdx.x;
  int pair = b >> 4, tile = b & 15;
  int s = pair >> 1, n = pair & 1;
  int t = threadIdx.x, lane = t & 63, wv = t >> 6;

  __shared__ float xs[C_ * 32];        // x tile [c][r] (32 rows)
  __shared__ float ybuf[12 * YPITCH];  // y chunk [cr][p]
  __shared__ float mus[C_];
  __shared__ unsigned cm[M_];          // block colmax (uint bits), p = lane+64k
  __shared__ float red[8];
  __shared__ unsigned arr;
  __shared__ int lastflag;

  int h0 = hi[s] - PADK, w0 = wi[s] - PADK, d0 = di[s] - PADK;
  if (t < C_) mus[t] = ws[OFF_MU + s * C_ + t] * (1.0f / 1024.0f);
  cm[t] = 0u;                          // t covers all 512 p slots

  // stage raw x tile: 1536 elems; i -> (c = i>>5, r = i&31), m = tile*32+r
#pragma unroll
  for (int j = 0; j < 3; ++j) {
    int i = t + 512 * j;
    int c = i >> 5, r = i & 31;
    int m = tile * 32 + r;
    xs[c * 32 + r] =
        x[gidx(n, c, h0 + (m >> 6), w0 + ((m >> 3) & 7), d0 + (m & 7))];
  }
  __syncthreads();

  // center + per-column normalize: 16-thread group per column (32 cols).
  {
    int col = t >> 4, sub = t & 15;    // sub covers channels sub, sub+16, sub+32
    float v0 = xs[sub * 32 + col] - mus[sub];
    float v1 = xs[(sub + 16) * 32 + col] - mus[sub + 16];
    float v2 = xs[(sub + 32) * 32 + col] - mus[sub + 32];
    float ss = v0 * v0 + v1 * v1 + v2 * v2;
    ss += __shfl_xor(ss, 8); ss += __shfl_xor(ss, 4);
    ss += __shfl_xor(ss, 2); ss += __shfl_xor(ss, 1);
    float sc = 1.0f / fmaxf(sqrtf(ss), 1e-12f);
    xs[sub * 32 + col] = v0 * sc;
    xs[(sub + 16) * 32 + col] = v1 * sc;
    xs[(sub + 32) * 32 + col] = v2 * sc;
  }

  float acc[4][8];
#pragma unroll
  for (int r = 0; r < 4; ++r)
#pragma unroll
    for (int k = 0; k < 8; ++k) acc[r][k] = 0.f;

  const float* ysrc = ws + OFF_GY + (s * 96 + n) * 512;
  for (int chunk = 0; chunk < 4; ++chunk) {
    __syncthreads();                   // prev chunk consumed / x-norm done
#pragma unroll
    for (int i = 0; i < 3; ++i) {      // stage 12 channels: 1536 float4s
      int li = t + 512 * i;
      int cr = li >> 7, p4 = (li & 127) << 2;
      *(float4*)(ybuf + cr * YPITCH + p4) =
          *(const float4*)(ysrc + (chunk * 12 + cr) * 1024 + p4);
    }
    __syncthreads();
#pragma unroll
    for (int cr = 0; cr < 12; ++cr) {
      float yv[8];
#pragma unroll
      for (int k = 0; k < 8; ++k) yv[k] = ybuf[cr * YPITCH + lane + 64 * k];
      int c = chunk * 12 + cr;
      float4 xv = *(const float4*)(xs + c * 32 + wv * 4);  // wave-uniform
#pragma unroll
      for (int k = 0; k < 8; ++k) {
        acc[0][k] += xv.x * yv[k];
        acc[1][k] += xv.y * yv[k];
        acc[2][k] += xv.z * yv[k];
        acc[3][k] += xv.w * yv[k];
      }
    }
  }

  // epilogue: per-row min -> softmax -> wave colmax -> LDS colmax
  float cm2[8];
#pragma unroll
  for (int k = 0; k < 8; ++k) cm2[k] = 0.f;
#pragma unroll
  for (int r = 0; r < 4; ++r) {
    float dmin = 3.4e38f;
#pragma unroll
    for (int k = 0; k < 8; ++k) {
      float d = 1.0f - acc[r][k];
      acc[r][k] = d;
      dmin = fminf(dmin, d);
    }
#pragma unroll
    for (int off = 32; off; off >>= 1) dmin = fminf(dmin, __shfl_xor(dmin, off));
    float inv = 2.0f / (dmin + 1e-5f); // logits <= 2, no overflow
    float e[8], sm = 0.f;
#pragma unroll
    for (int k = 0; k < 8; ++k) {
      e[k] = __expf(2.0f - acc[r][k] * inv);
      sm += e[k];
    }
#pragma unroll
    for (int off = 32; off; off >>= 1) sm += __shfl_xor(sm, off);
    float rs = 1.0f / sm;
#pragma unroll
    for (int k = 0; k < 8; ++k) cm2[k] = fmaxf(cm2[k], e[k] * rs);
  }
#pragma unroll
  for (int k = 0; k < 8; ++k)          // LDS pre-reduce (p = lane + 64k)
    atomicMax(&cm[lane + 64 * k], __float_as_uint(cm2[k]));
  __syncthreads();

  unsigned* cmu = (unsigned*)(ws + OFF_CM) + pair * M_;
  if (cm[t]) atomicMax(&cmu[t], cm[t]);   // 1 global atomic per thread

  // ---- fused final: last block per pair reduces; last pair writes out ----
  __threadfence();
  if (t == 0) arr = atomicAdd((unsigned*)(ws + OFF_CNT) + pair, 1u);
  __syncthreads();
  if (arr == 15) {
    float sum = __uint_as_float(atomicOr(&cmu[t], 0u));   // coherent read
#pragma unroll
    for (int off = 32; off; off >>= 1) sum += __shfl_xor(sum, off);
    if (lane == 0) red[wv] = sum;
    if (t == 0) lastflag = 0;
    __syncthreads();
    if (t == 0) {
      float tot = 0.f;
#pragma unroll
      for (int i = 0; i < 8; ++i) tot += red[i];
      float loss = -logf(tot * (1.0f / 512.0f) + 1e-5f);
      atomicExch((unsigned*)(ws + OFF_PL) + pair, __float_as_uint(loss));
      __threadfence();
      unsigned d = atomicAdd((unsigned*)(ws + OFF_ALL), 1u);
      if (d == PAIRS - 1) lastflag = 1;
    }
    __syncthreads();
    if (lastflag && t < 32) {          // parallel 20-loss readback
      float v = (t < PAIRS)
                    ? __uint_as_float(atomicOr((unsigned*)(ws + OFF_PL) + t, 0u))
                    : 0.f;
#pragma unroll
      for (int off = 16; off; off >>= 1) v += __shfl_xor(v, off);
      if (t == 0) out[0] = v * (1.0f / (float)PAIRS);
    }
  }
}

extern "C" void kernel_launch(void* const* d_in, const int* in_sizes, int n_in,
                              void* d_out, int out_size, void* d_ws, size_t ws_size,
                              hipStream_t stream) {
  const float* x = (const float*)d_in[0];
  const float* y = (const float*)d_in[1];
  const int* hi = (const int*)d_in[2];
  const int* wi = (const int*)d_in[3];
  const int* di = (const int*)d_in[4];
  float* ws = (float*)d_ws;
  float* out = (float*)d_out;

  hipMemsetAsync(ws + OFF_CM, 0, ZERO_N * sizeof(float), stream);
  k_gy<<<960, 256, 0, stream>>>(y, hi, wi, di, ws);
  k_ny<<<160, 256, 0, stream>>>(ws);
  k_main<<<PAIRS * 16, 512, 0, stream>>>(x, hi, wi, di, ws, out);
}